// Round 5
// baseline (15613.080 us; speedup 1.0000x reference)
//
#include <hip/hip_runtime.h>
#include <hip/hip_cooperative_groups.h>
#include <math.h>

namespace cg = cooperative_groups;

#define Bn 4096
#define Tn 128
#define Fn 96
#define Sn 128
#define Hn 512

typedef __attribute__((ext_vector_type(8))) short bf16x8;
typedef __attribute__((ext_vector_type(4))) float f32x4;

#define GC(p) ((const __attribute__((address_space(1))) void*)(p))
#define LC(p) ((__attribute__((address_space(3))) void*)(p))

__device__ __forceinline__ short tobf(float f){
  unsigned u = __float_as_uint(f);
  unsigned r = (u + 0x7fffu + ((u>>16)&1u)) >> 16;
  return (short)r;
}
__device__ __forceinline__ float bf2f(short s){
  return __uint_as_float(((unsigned)(unsigned short)s)<<16);
}
__device__ __forceinline__ float sigmf_(float x){ return 1.0f/(1.0f+expf(-x)); }

// stage `rows` rows (64 bf16 = 128B each) from gsrc into LDS tile with
// chunk-XOR swizzle (chunk ^= row&7). Linear LDS dest + inverse-swizzled
// global source (both-sides rule).
__device__ __forceinline__ void stage_tile(const short* gsrc, size_t sstride, int k0,
                                           short* lt, int rows, int wid, int lane, int nw){
  int calls = rows >> 3;
  for (int c = wid; c < calls; c += nw){
    int r = (c<<3) + (lane>>3);
    int ch = (lane&7) ^ (r&7);
    const short* gp = gsrc + (size_t)r*sstride + k0 + (ch<<3);
    __builtin_amdgcn_global_load_lds(GC(gp), LC(lt + (c<<9)), 16, 0, 0);
  }
}
__device__ __forceinline__ bf16x8 frag(const short* lt, int row, int ch){
  return *(const bf16x8*)(lt + (row<<6) + ((ch ^ (row&7))<<3));
}

// ---------- prologue: weight prepack ----------

__global__ void k_pack_td(const float* __restrict__ tdW, short* __restrict__ tdWp){
  int i = blockIdx.x*256 + threadIdx.x;            // 512*128
  if (i >= 512*128) return;
  int n = i>>7, k = i&127;
  tdWp[i] = (k < Fn) ? tobf(tdW[n*Fn + k]) : (short)0;
}
__global__ void k_pack_x(const float* __restrict__ realW, const float* __restrict__ histW,
                         const float* __restrict__ realb, const float* __restrict__ histb,
                         short* __restrict__ Wxp, float* __restrict__ bxp){
  int i = blockIdx.x*256 + threadIdx.x;            // 96*640
  if (i < Fn) bxp[i] = realb[i] + histb[i];
  if (i >= Fn*640) return;
  int f = i/640, k = i - f*640;
  float v = 0.f;
  if (k < 96) v = realW[f*Fn + k];
  else if (k < 608) v = histW[f*Hn + (k-96)];
  Wxp[i] = tobf(v);
}
__global__ void k_pack_g(const float* __restrict__ Wih, const float* __restrict__ Whh,
                         const float* __restrict__ bih, const float* __restrict__ bhh,
                         short* __restrict__ Wgp, float* __restrict__ bgp){
  int i = blockIdx.x*256 + threadIdx.x;            // 8*256*704
  if (i >= 8*256*704) return;
  int k = i % 704; int nc = i / 704;
  int pb = nc >> 8, ncol = nc & 255;
  int jj = ncol >> 2, g = ncol & 3;
  int n = g*Hn + pb*64 + jj;
  float v;
  if (k < 512) v = Whh[(size_t)n*Hn + k];
  else if (k < 608) v = Wih[(size_t)n*192 + (k-512)];
  else v = Wih[(size_t)n*192 + 96 + (k-608)];
  Wgp[i] = tobf(v);
  if (k == 0) bgp[nc] = bih[n] + bhh[n];
}

// ---------- prologue math (fp32) ----------

__global__ void k_static(const float* __restrict__ statics, const float* __restrict__ smask,
                         const float* __restrict__ frW, const float* __restrict__ frb,
                         float* __restrict__ s_c){
  __shared__ float row[Sn];
  int b = blockIdx.x, j = threadIdx.x;
  row[j] = statics[b*Sn + j];
  __syncthreads();
  float acc = frb[j];
  #pragma unroll 4
  for (int k = 0; k < Sn; k++) acc += row[k] * frW[j*Sn + k];
  float m = smask[b*Sn + j];
  s_c[b*Sn + j] = m * row[j] + (1.0f - m) * acc;
}

template<int K, int N, bool RELU>
__global__ void k_mlp(const float* __restrict__ in, const float* __restrict__ W,
                      const float* __restrict__ bias, float* __restrict__ out){
  __shared__ float row[K];
  int b = blockIdx.x;
  for (int i = threadIdx.x; i < K; i += blockDim.x) row[i] = in[b*K + i];
  __syncthreads();
  for (int n = threadIdx.x; n < N; n += blockDim.x){
    float acc = bias[n];
    #pragma unroll 4
    for (int k = 0; k < K; k++) acc += row[k] * W[n*K + k];
    if (RELU) acc = fmaxf(acc, 0.0f);
    out[b*N + n] = acc;
  }
}

__global__ void k_masksum(const float* __restrict__ masks, float* __restrict__ den){
  int t = blockIdx.x, tid = threadIdx.x;
  float s = 0.f;
  for (int i = tid; i < Bn*Fn; i += 256){
    int b = i / Fn, f = i - b*Fn;
    s += masks[((size_t)b*Tn + t)*Fn + f];
  }
  __shared__ float red[256];
  red[tid] = s; __syncthreads();
  for (int o = 128; o > 0; o >>= 1){ if (tid < o) red[tid] += red[tid + o]; __syncthreads(); }
  if (tid == 0) den[t] = red[0];
}

// ---------- the persistent cooperative scan kernel ----------
// grid = 256 blocks x 512 threads; loops t internally with grid.sync().
// Phase P: 16 rows/block -> decay GEMM + xc GEMM (A2 tile stays in LDS).
// Phase G: 128x256 gates GEMM tile + fused LSTM epilogue (round-4 verified).
__global__ __launch_bounds__(512) void k_seq(
    const float* __restrict__ values, const float* __restrict__ masks,
    const float* __restrict__ deltas, const float* __restrict__ tdb,
    const float* __restrict__ st,     const float* __restrict__ bxp,
    const float* __restrict__ bgp,
    const short* __restrict__ tdWp,   const short* __restrict__ Wxp,
    const short* __restrict__ Wgp,
    short* __restrict__ inp, float* __restrict__ h_g, float* __restrict__ c_g,
    float* __restrict__ num, float* __restrict__ out_imp){
  __shared__ __align__(16) short lds_main[2*24576];   // 96 KB (G: 2x[(128+256)x64])
  __shared__ short sm[16*96];
  __shared__ float wred[8];
  cg::grid_group grid = cg::this_grid();

  const int tid = threadIdx.x, lane = tid&63, wid = tid>>6;
  const int bid = blockIdx.x;
  // P-phase overlay
  short* A2   = lds_main;            // 10 kt-tiles [16][64] (20 KB): [x(96)|hdec(512)|pad]
  short* Adel = lds_main + 10240;    // 2 kt-tiles [16][64] (4 KB): deltas, pad 96..128
  short* ldsB = lds_main + 12288;    // stage buffer (32 KB max)
  // G-phase buffers
  short* ldsG0 = lds_main;
  short* ldsG1 = lds_main + 24576;

  const int r0p = bid*16;
  const int mb = bid >> 3, pb = bid & 7;
  const int r0g = mb*128;

  for (int t = 0; t < Tn; t++){
    // ================= PHASE P =================
    // stage x/m/deltas for 16 rows; build A2 x-part, Adel, m-tile; write m to inp
    for (int i = tid; i < 16*96; i += 512){
      int r = i/96, f = i - r*96;
      size_t gi = ((size_t)(r0p + r)*Tn + t)*Fn + f;
      float xv = values[gi], mv = masks[gi], dv = deltas[gi];
      sm[r*96 + f] = tobf(mv);
      inp[(size_t)(r0p + r)*704 + 608 + f] = tobf(mv);
      int c = f & 63, kp = f >> 6;
      int sw = (((c>>3) ^ (r&7))<<3) + (c&7);
      A2[kp*1024 + r*64 + sw]   = tobf(xv);
      Adel[kp*1024 + r*64 + sw] = tobf(dv);
    }
    { // zero pads (keep finite for MFMA x zero-weights)
      int r = tid >> 5, c = 32 + (tid & 31);
      int sw = (((c>>3) ^ (r&7))<<3) + (c&7);
      Adel[1024 + r*64 + sw]   = 0;   // deltas k=96..128
      A2[9*1024 + r*64 + sw]   = 0;   // A2 k=608..640
    }
    __syncthreads();

    // decay GEMM: M=16, N=512 (2 halves of 256), K=128; B=tdWp streamed
    for (int nh = 0; nh < 2; nh++){
      f32x4 accd[2];
      accd[0]=(f32x4){0,0,0,0}; accd[1]=(f32x4){0,0,0,0};
      for (int kp = 0; kp < 2; kp++){
        __syncthreads();
        stage_tile(tdWp + (size_t)(nh*256)*128, 128, kp*64, ldsB, 256, wid, lane, 8);
        __syncthreads();
        #pragma unroll
        for (int kk=0;kk<2;kk++){
          int ch = (kk<<2)+(lane>>4);
          int ar = lane&15;
          bf16x8 af = *(const bf16x8*)(Adel + kp*1024 + ar*64 + ((ch ^ (ar&7))<<3));
          #pragma unroll
          for (int n=0;n<2;n++){
            int rn = wid*32 + n*16 + (lane&15);
            bf16x8 bf = *(const bf16x8*)(ldsB + rn*64 + ((ch ^ (rn&7))<<3));
            accd[n] = __builtin_amdgcn_mfma_f32_16x16x32_bf16(af, bf, accd[n],0,0,0);
          }
        }
      }
      // gamma*h epilogue -> A2 (LDS) + inp (global)
      #pragma unroll
      for (int n=0;n<2;n++){
        int col = nh*256 + wid*32 + n*16 + (lane&15);
        float tb = tdb[col];
        #pragma unroll
        for (int reg=0;reg<4;reg++){
          int row = ((lane>>4)<<2)+reg;
          float v = accd[n][reg] + tb;
          float hd = h_g[(size_t)(r0p+row)*Hn + col] * __expf(-fmaxf(v,0.f));
          int k2 = 96 + col, c2 = k2 & 63, kt2 = k2 >> 6;
          A2[kt2*1024 + row*64 + ((((c2>>3) ^ (row&7)))<<3) + (c2&7)] = tobf(hd);
          inp[(size_t)(r0p+row)*704 + col] = tobf(hd);
        }
      }
    }

    // xc GEMM: M=16, N=96, K=640; A=A2 (LDS-resident), B=Wxp streamed
    f32x4 accx = (f32x4){0,0,0,0};
    for (int kp = 0; kp < 10; kp++){
      __syncthreads();
      stage_tile(Wxp, 640, kp*64, ldsB, 96, wid, lane, 8);
      __syncthreads();
      if (wid < 6){
        #pragma unroll
        for (int kk=0;kk<2;kk++){
          int ch = (kk<<2)+(lane>>4);
          int ar = lane&15;
          bf16x8 af = *(const bf16x8*)(A2 + kp*1024 + ar*64 + ((ch ^ (ar&7))<<3));
          int rn = wid*16 + (lane&15);
          bf16x8 bf = *(const bf16x8*)(ldsB + rn*64 + ((ch ^ (rn&7))<<3));
          accx = __builtin_amdgcn_mfma_f32_16x16x32_bf16(af, bf, accx,0,0,0);
        }
      }
    }
    float lsum = 0.f;
    if (wid < 6){
      int f = wid*16 + (lane&15);
      float bx = bxp[f];
      #pragma unroll
      for (int reg=0;reg<4;reg++){
        int row = ((lane>>4)<<2)+reg;
        float xc = accx[reg] + bx + st[(size_t)(r0p+row)*Fn + f];
        int c = f&63, kp = f>>6;
        float xv = bf2f(A2[kp*1024 + row*64 + ((((c>>3)^(row&7)))<<3) + (c&7)]);
        float mv = bf2f(sm[row*96 + f]);
        lsum += fabsf(xv - xc)*mv;
        float cc = mv*xv + (1.f-mv)*xc;
        inp[(size_t)(r0p+row)*704 + 512 + f] = tobf(cc);
        out_imp[((size_t)(r0p+row)*Tn + t)*Fn + f] = cc;
      }
    }
    #pragma unroll
    for (int o=32;o>0;o>>=1) lsum += __shfl_down(lsum, o);
    if (lane==0) wred[wid] = lsum;
    __syncthreads();
    if (tid==0){
      float s2=0.f;
      #pragma unroll
      for (int w2=0;w2<8;w2++) s2 += wred[w2];
      atomicAdd(&num[t], s2);
    }

    grid.sync();   // inp complete -> gates may read

    // ================= PHASE G =================
    {
      const short* gA = inp + (size_t)r0g*704;
      const short* gB = Wgp + (size_t)pb*256*704;
      const int wr = (wid>>2)*64, wc = (wid&3)*64;
      f32x4 acc[4][4];
      #pragma unroll
      for (int m=0;m<4;m++)
        #pragma unroll
        for (int n=0;n<4;n++) acc[m][n] = (f32x4){0,0,0,0};

      stage_tile(gA, 704, 0, ldsG0, 128, wid, lane, 8);
      stage_tile(gB, 704, 0, ldsG0 + 128*64, 256, wid, lane, 8);
      __syncthreads();

      for (int kg=0; kg<11; kg++){
        const short* lA = (kg&1) ? ldsG1 : ldsG0;
        const short* lB = lA + 128*64;
        if (kg < 10){
          short* nxt = (kg&1) ? ldsG0 : ldsG1;
          stage_tile(gA, 704, (kg+1)*64, nxt, 128, wid, lane, 8);
          stage_tile(gB, 704, (kg+1)*64, nxt + 128*64, 256, wid, lane, 8);
        }
        #pragma unroll
        for (int kk=0;kk<2;kk++){
          bf16x8 af[4], bfr[4];
          int ch = (kk<<2) + (lane>>4);
          #pragma unroll
          for (int m=0;m<4;m++) af[m] = frag(lA, wr + m*16 + (lane&15), ch);
          #pragma unroll
          for (int n=0;n<4;n++) bfr[n] = frag(lB, wc + n*16 + (lane&15), ch);
          #pragma unroll
          for (int m=0;m<4;m++)
            #pragma unroll
            for (int n=0;n<4;n++)
              acc[m][n] = __builtin_amdgcn_mfma_f32_16x16x32_bf16(af[m], bfr[n], acc[m][n], 0,0,0);
        }
        __syncthreads();
      }

      // fused LSTM epilogue (gates interleaved ncol=jj*4+g; 4-lane shfl transpose)
      const int g = lane&3;
      float bgv[4];
      #pragma unroll
      for (int n=0;n<4;n++) bgv[n] = bgp[pb*256 + wc + n*16 + (lane&15)];
      const float s  = (g==2) ? 2.0f : -1.0f;
      const float ca = (g==2) ? -2.0f : 1.0f;
      const float cb = (g==2) ? 1.0f : 0.0f;
      #pragma unroll
      for (int m=0;m<4;m++){
        int row = r0g + wr + m*16 + ((lane>>4)<<2) + g;
        #pragma unroll
        for (int n=0;n<4;n++){
          float b = bgv[n];
          float q0 = 1.f/(1.f+__expf(s*(acc[m][n][0]+b))); float a0 = q0*ca+cb;
          float q1 = 1.f/(1.f+__expf(s*(acc[m][n][1]+b))); float a1 = q1*ca+cb;
          float q2 = 1.f/(1.f+__expf(s*(acc[m][n][2]+b))); float a2 = q2*ca+cb;
          float q3 = 1.f/(1.f+__expf(s*(acc[m][n][3]+b))); float a3 = q3*ca+cb;
          int i1=g^1, i2=g^2, i3=g^3;
          float p1 = (i1==0)?a0:(i1==1)?a1:(i1==2)?a2:a3;
          float p2 = (i2==0)?a0:(i2==1)?a1:(i2==2)?a2:a3;
          float p3 = (i3==0)?a0:(i3==1)?a1:(i3==2)?a2:a3;
          float ow = (g==0)?a0:(g==1)?a1:(g==2)?a2:a3;
          float t1 = __shfl_xor(p1, 1, 64);
          float t2 = __shfl_xor(p2, 2, 64);
          float t3 = __shfl_xor(p3, 3, 64);
          float si = (g==0)?ow:(g==1)?t1:(g==2)?t2:t3;
          float sf = (g==1)?ow:(g==0)?t1:(g==3)?t2:t3;
          float tg = (g==2)?ow:(g==3)?t1:(g==0)?t2:t3;
          float so = (g==3)?ow:(g==2)?t1:(g==1)?t2:t3;
          int jh = pb*64 + ((wc + n*16 + (lane&15))>>2);
          size_t idx = (size_t)row*Hn + jh;
          float co = c_g[idx];
          float cn = sf*co + si*tg;
          float targ = fminf(fmaxf(2.0f*cn,-60.f),60.f);
          float e = __expf(targ); float th = (e-1.f)/(e+1.f);
          c_g[idx] = cn;
          h_g[idx] = so*th;
        }
      }
    }

    grid.sync();   // h/c complete -> next step's P may read
  }
}

// ---------- epilogue ----------

__global__ void k_out(const float* __restrict__ h_g, const float* __restrict__ outW,
                      const float* __restrict__ outb, const float* __restrict__ labels,
                      float* __restrict__ out_sig, float* __restrict__ yacc){
  int b = blockIdx.x, lane = threadIdx.x;
  float s = 0.f;
  for (int k = lane; k < Hn; k += 64) s += h_g[(size_t)b*Hn + k] * outW[k];
  #pragma unroll
  for (int o = 32; o > 0; o >>= 1) s += __shfl_down(s, o);
  if (lane == 0){
    float z = s + outb[0];
    out_sig[b] = sigmf_(z);
    float yl = fmaxf(z, 0.f) - z*labels[b] + log1pf(expf(-fabsf(z)));
    atomicAdd(yacc, yl);
  }
}

__global__ void k_loss(const float* __restrict__ realW, const float* __restrict__ histW,
                       const float* __restrict__ stW,   const float* __restrict__ frW,
                       const float* __restrict__ num,   const float* __restrict__ den,
                       const float* __restrict__ yacc,  float* __restrict__ out0){
  int tid = threadIdx.x;
  float r1 = 0.f;
  for (int i = tid; i < Fn*Fn; i += 256) r1 += fabsf(realW[i]);
  for (int i = tid; i < Fn*Hn; i += 256) r1 += fabsf(histW[i]);
  for (int i = tid; i < Fn*Sn; i += 256) r1 += fabsf(stW[i]);
  float rd = 0.f;
  for (int i = tid; i < Fn; i += 256) rd += fabsf(realW[i*Fn + i]);
  float fd = 0.f;
  for (int i = tid; i < Sn; i += 256) fd += fabsf(frW[i*Sn + i]);
  float xl = 0.f;
  for (int t = tid; t < Tn; t += 256) xl += num[t] / (den[t] + 1e-5f);
  float v = 0.01f*r1 + 0.1f*rd + 0.3f*xl + 0.03f*fd;
  __shared__ float red[256];
  red[tid] = v; __syncthreads();
  for (int o = 128; o > 0; o >>= 1){ if (tid < o) red[tid] += red[tid + o]; __syncthreads(); }
  if (tid == 0) out0[0] = red[0] + yacc[0] / (float)Bn;
}

// ---------- launch ----------

extern "C" void kernel_launch(void* const* d_in, const int* in_sizes, int n_in,
                              void* d_out, int out_size, void* d_ws, size_t ws_size,
                              hipStream_t stream){
  const float* values = (const float*)d_in[0];
  const float* masks  = (const float*)d_in[1];
  const float* deltas = (const float*)d_in[2];
  const float* statics= (const float*)d_in[3];
  const float* smask  = (const float*)d_in[4];
  const float* labels = (const float*)d_in[5];
  const float* frW = (const float*)d_in[6];
  const float* frb = (const float*)d_in[7];
  const float* d1W = (const float*)d_in[8];
  const float* d1b = (const float*)d_in[9];
  const float* d2W = (const float*)d_in[10];
  const float* d2b = (const float*)d_in[11];
  const float* d3W = (const float*)d_in[12];
  const float* d3b = (const float*)d_in[13];
  const float* tdW = (const float*)d_in[14];
  const float* tdb = (const float*)d_in[15];
  const float* histW = (const float*)d_in[16];
  const float* histb = (const float*)d_in[17];
  const float* stW = (const float*)d_in[18];
  const float* stb = (const float*)d_in[19];
  const float* realW = (const float*)d_in[20];
  const float* realb = (const float*)d_in[21];
  const float* Wih = (const float*)d_in[22];
  const float* Whh = (const float*)d_in[23];
  const float* bih = (const float*)d_in[24];
  const float* bhh = (const float*)d_in[25];
  const float* outW = (const float*)d_in[26];
  const float* outb = (const float*)d_in[27];

  float* out0    = (float*)d_out;
  float* out_sig = out0 + 1;
  float* out_imp = out0 + 1 + Bn;

  float* wsf  = (float*)d_ws;
  float* s_c  = wsf;  wsf += Bn*Sn;
  float* h    = wsf;  wsf += (size_t)Bn*Hn;
  float* c    = wsf;  wsf += (size_t)Bn*Hn;
  float* st   = wsf;  wsf += Bn*Fn;
  float* tmp  = wsf;  wsf += (size_t)Bn*Hn;
  float* den  = wsf;  wsf += Tn;
  float* num  = wsf;  wsf += Tn;
  float* yacc = num + Tn;           // contiguous with num, zeroed together
  wsf += 1;
  float* bxp  = wsf;  wsf += 128;
  float* bgp  = wsf;  wsf += 2048;
  size_t off = ((size_t)(wsf - (float*)d_ws) + 3u) & ~(size_t)3u;
  short* wss  = (short*)((float*)d_ws + off);
  short* tdWp = wss;  wss += 512*128;
  short* Wxp  = wss;  wss += 96*640;
  short* Wgp  = wss;  wss += (size_t)8*256*704;
  short* inp  = wss;  wss += (size_t)Bn*704;

  hipMemsetAsync(c,   0, (size_t)Bn*Hn*sizeof(float), stream);
  hipMemsetAsync(num, 0, (Tn + 1)*sizeof(float), stream);

  // prepacks
  k_pack_td<<<(512*128+255)/256, 256, 0, stream>>>(tdW, tdWp);
  k_pack_x <<<(96*640+255)/256, 256, 0, stream>>>(realW, histW, realb, histb, Wxp, bxp);
  k_pack_g <<<(8*256*704+255)/256, 256, 0, stream>>>(Wih, Whh, bih, bhh, Wgp, bgp);

  // prologue math
  k_static<<<Bn, Sn, 0, stream>>>(statics, smask, frW, frb, s_c);
  k_mlp<Sn, Hn, true ><<<Bn, 256, 0, stream>>>(s_c, d1W, d1b, tmp);
  k_mlp<Hn, Hn, true ><<<Bn, 256, 0, stream>>>(tmp, d2W, d2b, tmp);
  k_mlp<Hn, Hn, true ><<<Bn, 256, 0, stream>>>(tmp, d3W, d3b, h);
  k_mlp<Sn, Fn, false><<<Bn, 256, 0, stream>>>(s_c, stW, stb, st);
  k_masksum<<<Tn, 256, 0, stream>>>(masks, den);

  // persistent cooperative scan: the whole t-loop in one launch
  {
    void* kargs[] = {
      (void*)&values, (void*)&masks, (void*)&deltas, (void*)&tdb,
      (void*)&st, (void*)&bxp, (void*)&bgp,
      (void*)&tdWp, (void*)&Wxp, (void*)&Wgp,
      (void*)&inp, (void*)&h, (void*)&c, (void*)&num, (void*)&out_imp
    };
    hipLaunchCooperativeKernel((void*)k_seq, dim3(256), dim3(512), kargs, 0, stream);
  }

  k_out<<<Bn, 64, 0, stream>>>(h, outW, outb, labels, out_sig, yacc);
  k_loss<<<1, 256, 0, stream>>>(realW, histW, stW, frW, num, den, yacc, out0);
}